// Round 1
// baseline (1478.093 us; speedup 1.0000x reference)
//
#include <hip/hip_runtime.h>
#include <math.h>

// GCN: 3 layers. Per layer: t = h @ W; agg = segment_sum(t[src]*val, dst); h' = act(agg + b)
// N=100000, E=3200000, F=64, C1=32, C2=64, C3=19.

// ---------------- GEMM 1: t1 = x @ W1   (N x 64) @ (64 x 32) ----------------
__global__ __launch_bounds__(256) void gemm1_k(const float* __restrict__ x,
                                               const float* __restrict__ W1,
                                               float* __restrict__ t1, int N) {
    __shared__ float xs[64][64];   // 16 KB
    __shared__ float ws[64][32];   // 8 KB
    const int tid = threadIdx.x;
    const int row0 = blockIdx.x * 64;

    for (int i = tid; i < 64 * 32; i += 256) ws[i >> 5][i & 31] = W1[i];
    // x tile as float4: 64 rows * 16 float4
    for (int i = tid; i < 64 * 16; i += 256) {
        int r = i >> 4, c4 = i & 15;
        float4 v = make_float4(0.f, 0.f, 0.f, 0.f);
        int row = row0 + r;
        if (row < N) v = reinterpret_cast<const float4*>(x + (size_t)row * 64)[c4];
        *reinterpret_cast<float4*>(&xs[r][c4 * 4]) = v;
    }
    __syncthreads();

    const int col = tid & 31, rg = tid >> 5;  // 8 row groups
    for (int rr = 0; rr < 8; ++rr) {
        int r = rg + rr * 8;
        float acc = 0.f;
#pragma unroll
        for (int k = 0; k < 64; ++k) acc += xs[r][k] * ws[k][col];
        int row = row0 + r;
        if (row < N) t1[(size_t)row * 32 + col] = acc;
    }
}

// ---------------- GEMM 2: t2 = elu(agg1 + b1) @ W2   (N x 32) @ (32 x 64) ----------------
__global__ __launch_bounds__(256) void gemm2_k(const float* __restrict__ agg1,
                                               const float* __restrict__ b1,
                                               const float* __restrict__ W2,
                                               float* __restrict__ t2, int N) {
    __shared__ float hs[64][32];   // 8 KB
    __shared__ float ws[32][64];   // 8 KB
    const int tid = threadIdx.x;
    const int row0 = blockIdx.x * 64;

    for (int i = tid; i < 32 * 64; i += 256) ws[i >> 6][i & 63] = W2[i];
    for (int i = tid; i < 64 * 32; i += 256) {
        int r = i >> 5, k = i & 31;
        float v = 0.f;
        int row = row0 + r;
        if (row < N) {
            v = agg1[(size_t)row * 32 + k] + b1[k];
            v = (v > 0.f) ? v : expm1f(v);   // elu
        }
        hs[r][k] = v;
    }
    __syncthreads();

    const int col = tid & 63, rg = tid >> 6;  // 4 row groups
    for (int rr = 0; rr < 16; ++rr) {
        int r = rg + rr * 4;
        float acc = 0.f;
#pragma unroll
        for (int k = 0; k < 32; ++k) acc += hs[r][k] * ws[k][col];
        int row = row0 + r;
        if (row < N) t2[(size_t)row * 64 + col] = acc;
    }
}

// ---------------- GEMM 3: t3 = elu(agg2 + b2) @ W4   (N x 64) @ (64 x 19) ----------------
__global__ __launch_bounds__(256) void gemm3_k(const float* __restrict__ agg2,
                                               const float* __restrict__ b2,
                                               const float* __restrict__ W4,
                                               float* __restrict__ t3, int N) {
    __shared__ float hs[64][64];   // 16 KB
    __shared__ float ws[64][19];   // ~4.8 KB
    const int tid = threadIdx.x;
    const int row0 = blockIdx.x * 64;

    for (int i = tid; i < 64 * 19; i += 256) ws[i / 19][i % 19] = W4[i];
    for (int i = tid; i < 64 * 64; i += 256) {
        int r = i >> 6, k = i & 63;
        float v = 0.f;
        int row = row0 + r;
        if (row < N) {
            v = agg2[(size_t)row * 64 + k] + b2[k];
            v = (v > 0.f) ? v : expm1f(v);
        }
        hs[r][k] = v;
    }
    __syncthreads();

    const int col = tid & 31, rg = tid >> 5;  // 8 row groups, cols 0..18 active
    if (col < 19) {
        for (int rr = 0; rr < 8; ++rr) {
            int r = rg + rr * 8;
            float acc = 0.f;
#pragma unroll
            for (int k = 0; k < 64; ++k) acc += hs[r][k] * ws[k][col];
            int row = row0 + r;
            if (row < N) t3[(size_t)row * 19 + col] = acc;
        }
    }
}

// ---------------- scatter-add: agg[dst] += t[src] * val ----------------
template <int C>  // C power of two (32, 64)
__global__ __launch_bounds__(256) void scatter_k(const float* __restrict__ t,
                                                 const int* __restrict__ src,
                                                 const int* __restrict__ dst,
                                                 const float* __restrict__ vals,
                                                 float* __restrict__ agg, int E) {
    long long gid = (long long)blockIdx.x * 256 + threadIdx.x;
    if (gid >= (long long)E * C) return;
    int e = (int)(gid / C);
    int c = (int)(gid & (C - 1));
    int s = src[e], d = dst[e];
    float v = t[(size_t)s * C + c] * vals[e];
    atomicAdd(&agg[(size_t)d * C + c], v);
}

// C=19 variant: 32 lanes per edge, 19 active
__global__ __launch_bounds__(256) void scatter19_k(const float* __restrict__ t,
                                                   const int* __restrict__ src,
                                                   const int* __restrict__ dst,
                                                   const float* __restrict__ vals,
                                                   float* __restrict__ agg, int E) {
    long long gid = (long long)blockIdx.x * 256 + threadIdx.x;
    int e = (int)(gid >> 5);
    int c = (int)(gid & 31);
    if (e >= E || c >= 19) return;
    int s = src[e], d = dst[e];
    float v = t[(size_t)s * 19 + c] * vals[e];
    atomicAdd(&agg[(size_t)d * 19 + c], v);
}

// ---------------- softmax rows of 19: out = softmax(agg3 + b4) ----------------
__global__ __launch_bounds__(256) void softmax19_k(const float* __restrict__ agg3,
                                                   const float* __restrict__ b4,
                                                   float* __restrict__ out, int N) {
    int r = blockIdx.x * 256 + threadIdx.x;
    if (r >= N) return;
    float v[19];
    float m = -INFINITY;
#pragma unroll
    for (int c = 0; c < 19; ++c) {
        v[c] = agg3[(size_t)r * 19 + c] + b4[c];
        m = fmaxf(m, v[c]);
    }
    float s = 0.f;
#pragma unroll
    for (int c = 0; c < 19; ++c) {
        v[c] = expf(v[c] - m);
        s += v[c];
    }
    float inv = 1.f / s;
#pragma unroll
    for (int c = 0; c < 19; ++c) out[(size_t)r * 19 + c] = v[c] * inv;
}

extern "C" void kernel_launch(void* const* d_in, const int* in_sizes, int n_in,
                              void* d_out, int out_size, void* d_ws, size_t ws_size,
                              hipStream_t stream) {
    const float* x     = (const float*)d_in[0];
    const int*   esrc  = (const int*)d_in[1];
    const int*   edst  = (const int*)d_in[2];
    const float* evals = (const float*)d_in[3];
    const float* W1    = (const float*)d_in[4];
    const float* b1    = (const float*)d_in[5];
    const float* W2    = (const float*)d_in[6];
    const float* b2    = (const float*)d_in[7];
    const float* W4    = (const float*)d_in[8];
    const float* b4    = (const float*)d_in[9];

    const int N = in_sizes[0] / 64;   // 100000
    const int E = in_sizes[1];        // 3200000

    // workspace layout: two 64N-float regions, ping-ponged.
    float* region1 = (float*)d_ws;                   // t1 / t2 / t3
    float* region2 = region1 + (size_t)64 * N;       // agg1 / agg2 / agg3

    float* t1 = region1;   float* agg1 = region2;    // N*32 each
    float* t2 = region1;   float* agg2 = region2;    // N*64 each
    float* t3 = region1;   float* agg3 = region2;    // N*19 each

    const int rb = (N + 63) / 64;

    // layer 1
    gemm1_k<<<rb, 256, 0, stream>>>(x, W1, t1, N);
    hipMemsetAsync(agg1, 0, (size_t)N * 32 * sizeof(float), stream);
    {
        long long tot = (long long)E * 32;
        scatter_k<32><<<(unsigned)((tot + 255) / 256), 256, 0, stream>>>(t1, esrc, edst, evals, agg1, E);
    }
    // layer 2 (elu+bias fused into GEMM2 load)
    gemm2_k<<<rb, 256, 0, stream>>>(agg1, b1, W2, t2, N);
    hipMemsetAsync(agg2, 0, (size_t)N * 64 * sizeof(float), stream);
    {
        long long tot = (long long)E * 64;
        scatter_k<64><<<(unsigned)((tot + 255) / 256), 256, 0, stream>>>(t2, esrc, edst, evals, agg2, E);
    }
    // layer 3
    gemm3_k<<<rb, 256, 0, stream>>>(agg2, b2, W4, t3, N);
    hipMemsetAsync(agg3, 0, (size_t)N * 19 * sizeof(float), stream);
    {
        long long tot = (long long)E * 32;  // 32 lanes/edge, 19 active
        scatter19_k<<<(unsigned)((tot + 255) / 256), 256, 0, stream>>>(t3, esrc, edst, evals, agg3, E);
    }
    // softmax epilogue
    softmax19_k<<<(N + 255) / 256, 256, 0, stream>>>(agg3, b4, (float*)d_out, N);
}